// Round 6
// baseline (183.488 us; speedup 1.0000x reference)
//
#include <hip/hip_runtime.h>
#include <hip/hip_bf16.h>
#include <hip/hip_fp16.h>
#include <math.h>

// ---------------- problem constants ----------------
#define ROWS  16384           // B*S
#define DM    1024
#define DS    64
#define NUSE  928             // 512+256+128+32
#define NPAD  960             // padded to 15 tiles of 64
#define RPB   16              // rows per block
#define NBLK  (ROWS/RPB)      // 1024

typedef __attribute__((ext_vector_type(8))) short bf16x8;
typedef __attribute__((ext_vector_type(4))) float f32x4;

static __device__ inline f32x4 mfma16(bf16x8 a, bf16x8 b, f32x4 c) {
    return __builtin_amdgcn_mfma_f32_16x16x32_bf16(a, b, c, 0, 0, 0);
}

// split fp32 -> bf16 hi + bf16 lo (RNE both), v ~= hi + lo to ~2^-18 rel
static __device__ inline void bfsplit(float v, unsigned short& h, unsigned short& l) {
    unsigned u = __float_as_uint(v);
    unsigned hr = u + 0x7FFFu + ((u >> 16) & 1u);
    h = (unsigned short)(hr >> 16);
    float hf = __uint_as_float((unsigned)h << 16);
    float r = v - hf;
    unsigned ur = __float_as_uint(r);
    unsigned lr2 = ur + 0x7FFFu + ((ur >> 16) & 1u);
    l = (unsigned short)(lr2 >> 16);
}

// ---------------- workspace byte offsets ----------------
// eb frag-linear [kt2][q4][n960][j8] hi/lo: 122880 B each
// wb frag-linear [ktg32][q4][n64][j8] hi/lo: 131072 B each
// wpart fp32 [rc1024][960] = 3.93 MB
#define OFF_EBH  0LL
#define OFF_EBL  122880LL
#define OFF_WBH  245760LL
#define OFF_WBL  376832LL
#define OFF_WP   507904LL

// ---------------- k_prep: emb normalize+split AND W split (merged) ----------------
__global__ __launch_bounds__(256) void k_prep(const float* __restrict__ emb,
                                              const float* __restrict__ W,
                                              unsigned short* __restrict__ ebh,
                                              unsigned short* __restrict__ ebl,
                                              unsigned short* __restrict__ wbh,
                                              unsigned short* __restrict__ wbl) {
    if (blockIdx.x < 4) {
        int n = blockIdx.x * 256 + threadIdx.x;
        if (n >= NPAD) return;
        if (n >= NUSE) {
            #pragma unroll
            for (int d = 0; d < DS; d++) {
                int kt = d >> 5, q = (d >> 3) & 3, j = d & 7;
                int a = ((kt * 4 + q) * NPAD + n) * 8 + j;
                ebh[a] = 0; ebl[a] = 0;
            }
            return;
        }
        float ss = 0.f;
        #pragma unroll
        for (int d = 0; d < DS; d++) { float v = emb[n * DS + d]; ss = fmaf(v, v, ss); }
        float inv = 1.0f / sqrtf(ss);
        #pragma unroll
        for (int d = 0; d < DS; d++) {
            float v = emb[n * DS + d] * inv;
            unsigned short h, l; bfsplit(v, h, l);
            int kt = d >> 5, q = (d >> 3) & 3, j = d & 7;
            int a = ((kt * 4 + q) * NPAD + n) * 8 + j;
            ebh[a] = h; ebl[a] = l;
        }
    } else {
        int idx = (blockIdx.x - 4) * 256 + threadIdx.x;   // 0..2047
        int ktg = idx >> 6, n = idx & 63;
        #pragma unroll
        for (int q = 0; q < 4; q++) {
            #pragma unroll
            for (int j = 0; j < 8; j++) {
                int k = ktg * 32 + q * 8 + j;
                float v = W[k * DS + n];
                unsigned short h, l; bfsplit(v, h, l);
                int a = ((ktg * 4 + q) * 64 + n) * 8 + j;
                wbh[a] = h; wbl[a] = l;
            }
        }
    }
}

// ---------------- k_mega: fused x@W+b -> logits -> softmax -> weighted col-reduce ----------------
// 1024 blocks x 512 thr (8 waves), 16 rows/block. LDS = 40960 B -> 4 blocks/CU,
// 32 waves/CU (8/SIMD). __launch_bounds__(512,8) caps VGPR at 64.
// Phase A: 8 waves = 8-way K-split(128); direct-global x A-frags, split in regs,
//          partials to Cb (LDS). Cooperative 512-thread reduce + bias + split -> H frags.
// Phase 1: 8 waves x ~2 n-tiles: logits MFMA + exp -> Ph (fp16, aliases Cb) + Z partials.
// Phase 2: weighted column reduce from Ph -> wpart.
__global__ __launch_bounds__(512, 8) void k_mega(const float* __restrict__ x,
                                                 const float* __restrict__ bias,
                                                 const unsigned short* __restrict__ wbh,
                                                 const unsigned short* __restrict__ wbl,
                                                 const unsigned short* __restrict__ ebh,
                                                 const unsigned short* __restrict__ ebl,
                                                 const float* __restrict__ imp,
                                                 float* __restrict__ wpart) {
    __shared__ __align__(16) unsigned char smem[40960];
    unsigned short* Ph   = (unsigned short*)smem;            // [n960][18] fp16 (phase 1/2)
    float*          Cb   = (float*)smem;                     // [w8][lane64][16] fp32 (phase A, alias)
    unsigned short* Hh   = (unsigned short*)(smem + 34560);  // [kt2][q4][r16][j8]
    unsigned short* Hl   = (unsigned short*)(smem + 36608);
    float*          zslot = (float*)(smem + 38656);          // [w8][sl4][r16]
    float*          coefL = (float*)(smem + 40704);          // [r16][sl4]

    const int tid = threadIdx.x;
    const int rc = blockIdx.x;
    const long long row0 = (long long)rc * RPB;
    const int w = tid >> 6, lane = tid & 63, q = lane >> 4, lm = lane & 15;

    zslot[tid] = 0.f;   // 512 floats exactly

    // ======== phase A: h partials, direct-global A-frags, 8-way K-split ========
    {
        const int kg = w;
        const float* xp = &x[(row0 + lm) * (long long)DM + kg * 128 + q * 8];
        f32x4 acc[4];
        #pragma unroll
        for (int f = 0; f < 4; f++) { acc[f].x = 0.f; acc[f].y = 0.f; acc[f].z = 0.f; acc[f].w = 0.f; }

        #pragma unroll
        for (int ks = 0; ks < 4; ks++) {
            float4 v0 = *(const float4*)&xp[ks * 32];
            float4 v1 = *(const float4*)&xp[ks * 32 + 4];
            union { bf16x8 v; unsigned short s[8]; } ah, al;
            bfsplit(v0.x, ah.s[0], al.s[0]); bfsplit(v0.y, ah.s[1], al.s[1]);
            bfsplit(v0.z, ah.s[2], al.s[2]); bfsplit(v0.w, ah.s[3], al.s[3]);
            bfsplit(v1.x, ah.s[4], al.s[4]); bfsplit(v1.y, ah.s[5], al.s[5]);
            bfsplit(v1.z, ah.s[6], al.s[6]); bfsplit(v1.w, ah.s[7], al.s[7]);
            const int ktg = kg * 4 + ks;
            #pragma unroll
            for (int f = 0; f < 4; f++) {
                const int ba = ((ktg * 4 + q) * 64 + f * 16 + lm) * 8;
                const bf16x8 b_h = *(const bf16x8*)&wbh[ba];
                const bf16x8 b_l = *(const bf16x8*)&wbl[ba];
                acc[f] = mfma16(ah.v, b_h, acc[f]);
                acc[f] = mfma16(ah.v, b_l, acc[f]);
                acc[f] = mfma16(al.v, b_h, acc[f]);
            }
        }
        #pragma unroll
        for (int f = 0; f < 4; f++)
            *(f32x4*)&Cb[(w * 64 + lane) * 16 + f * 4] = acc[f];
    }
    __syncthreads();

    // ======== cooperative K-reduce + bias + split -> H frags ========
    #pragma unroll
    for (int ee = 0; ee < 2; ee++) {
        const int e = tid * 2 + ee;           // 0..1023: C-element (lane L, reg r)
        float s = 0.f;
        #pragma unroll
        for (int g = 0; g < 8; g++) s += Cb[g * 1024 + e];
        const int L = e >> 4, r = e & 15, f = r >> 2, t = r & 3;
        const int row = (L >> 4) * 4 + t;
        const int col = f * 16 + (L & 15);
        s += bias[col];
        unsigned short hh, ll; bfsplit(s, hh, ll);
        const int kt = col >> 5, qH = (col >> 3) & 3, j = col & 7;
        const int hidx = ((kt * 4 + qH) * RPB + row) * 8 + j;
        Hh[hidx] = hh; Hl[hidx] = ll;
    }
    __syncthreads();   // H visible; Cb reads done -> Ph region reusable

    // ======== phase 1: logits + exp -> Ph, Z partials ========
    bf16x8 a_h[2], a_l[2];
    #pragma unroll
    for (int kt = 0; kt < 2; kt++) {
        const int ab = ((kt * 4 + q) * RPB + lm) * 8;
        a_h[kt] = *(const bf16x8*)&Hh[ab];
        a_l[kt] = *(const bf16x8*)&Hl[ab];
    }

    #pragma unroll
    for (int v = 0; v < 2; v++) {
        const int nt = w + v * 8;
        if (nt > 14) continue;
        f32x4 acc[4];
        #pragma unroll
        for (int f = 0; f < 4; f++) { acc[f].x = 0.f; acc[f].y = 0.f; acc[f].z = 0.f; acc[f].w = 0.f; }
        #pragma unroll
        for (int kt = 0; kt < 2; kt++) {
            #pragma unroll
            for (int f = 0; f < 4; f++) {
                const int bb = ((kt * 4 + q) * NPAD + nt * 64 + f * 16 + lm) * 8;
                const bf16x8 b_h = *(const bf16x8*)&ebh[bb];
                const bf16x8 b_l = *(const bf16x8*)&ebl[bb];
                acc[f] = mfma16(a_h[kt], b_h, acc[f]);
                acc[f] = mfma16(a_h[kt], b_l, acc[f]);
                acc[f] = mfma16(a_l[kt], b_h, acc[f]);
            }
        }
        const int sl = (nt < 8) ? 0 : (nt < 12) ? 1 : (nt < 14) ? 2 : 3;
        float s0 = 0.f, s1 = 0.f, s2 = 0.f, s3 = 0.f;
        #pragma unroll
        for (int f = 0; f < 4; f++) {
            float e0 = __expf(acc[f][0]);
            float e1 = __expf(acc[f][1]);
            float e2 = __expf(acc[f][2]);
            float e3 = __expf(acc[f][3]);
            const int n = nt * 64 + f * 16 + lm;
            unsigned short p0 = __half_as_ushort(__float2half(e0));
            unsigned short p1 = __half_as_ushort(__float2half(e1));
            unsigned short p2 = __half_as_ushort(__float2half(e2));
            unsigned short p3 = __half_as_ushort(__float2half(e3));
            // Ph[n][row]: rows q*4..q*4+3 -> two dword stores (4-aligned, stride-9-bank)
            *(unsigned*)&Ph[n * 18 + q * 4]     = (unsigned)p0 | ((unsigned)p1 << 16);
            *(unsigned*)&Ph[n * 18 + q * 4 + 2] = (unsigned)p2 | ((unsigned)p3 << 16);
            if (nt * 64 + f * 16 < NUSE) {   // exclude pad cols (nt14 f2,f3)
                s0 += e0; s1 += e1; s2 += e2; s3 += e3;
            }
        }
        #pragma unroll
        for (int off = 1; off < 16; off <<= 1) {
            s0 += __shfl_xor(s0, off); s1 += __shfl_xor(s1, off);
            s2 += __shfl_xor(s2, off); s3 += __shfl_xor(s3, off);
        }
        if (lm < 4) {
            float sv = (lm == 0) ? s0 : (lm == 1) ? s1 : (lm == 2) ? s2 : s3;
            zslot[(w * 4 + sl) * RPB + q * 4 + lm] += sv;   // per-wave slots: no race
        }
    }
    __syncthreads();

    // ---- Z + coef ----
    if (tid < RPB) {
        const int r = tid;
        const float im = imp[row0 + r];
        #pragma unroll
        for (int sl = 0; sl < 4; sl++) {
            float Z = 0.f;
            #pragma unroll
            for (int g = 0; g < 8; g++) Z += zslot[(g * 4 + sl) * RPB + r];
            coefL[r * 4 + sl] = im / Z;
        }
    }
    __syncthreads();

    // ======== phase 2: weighted column reduce ========
    for (int nn = tid; nn < NUSE; nn += 512) {
        const int sl = (nn < 512) ? 0 : (nn < 768) ? 1 : (nn < 896) ? 2 : 3;
        float acc = 0.f;
        #pragma unroll
        for (int rb = 0; rb < 8; rb++) {
            const unsigned pk = *(const unsigned*)&Ph[nn * 18 + rb * 2];
            float v0 = __half2float(__ushort_as_half((unsigned short)(pk & 0xFFFF)));
            float v1 = __half2float(__ushort_as_half((unsigned short)(pk >> 16)));
            acc = fmaf(coefL[(rb * 2 + 0) * 4 + sl], v0, acc);
            acc = fmaf(coefL[(rb * 2 + 1) * 4 + sl], v1, acc);
        }
        wpart[(long long)rc * NPAD + nn] = acc;
    }
}

// ---------------- k_out: reduce wpart (128 chunks/batch), ranks, outputs ----------------
__global__ __launch_bounds__(512) void k_out(const float* __restrict__ wpart,
                                             float* __restrict__ out) {
    const int b = blockIdx.x;
    const int tid = threadIdx.x;
    __shared__ float w_s[NUSE];
    __shared__ int   rk[NUSE];

    for (int n = tid; n < NUSE; n += 512) {
        float s = 0.f;
        #pragma unroll 4
        for (int c = 0; c < 128; c++)
            s += wpart[(long long)(b * 128 + c) * NPAD + n];
        w_s[n] = s;
        if (n < 512)      out[3072 + (long long)b * 512 + n] = s;
        else if (n < 768) out[7168 + (long long)b * 256 + (n - 512)] = s;
    }
    __syncthreads();

    for (int n = tid; n < NUSE; n += 512) {
        int lo, hi;
        if (n < 512)      { lo = 0;   hi = 512; }
        else if (n < 768) { lo = 512; hi = 768; }
        else if (n < 896) { lo = 768; hi = 896; }
        else              { lo = 896; hi = NUSE; }
        float wn = w_s[n];
        int r = 0;
        for (int m = lo; m < hi; m++) {
            float wm = w_s[m];
            r += (wm > wn) || ((wm == wn) && (m < n));
        }
        rk[n] = r;
    }
    __syncthreads();

    if (tid < 512) {
        int n = tid;
        if (rk[n] < 64) {
            int pos = 0;
            for (int m = 0; m < n; m++) pos += (rk[m] < 64) ? 1 : 0;
            out[(long long)b * 64 + pos] = (float)n;
        }
    }
    if (tid < 256) {
        int n = 512 + tid;
        if (rk[n] < 32) {
            int pos = 0;
            for (int m = 512; m < n; m++) pos += (rk[m] < 32) ? 1 : 0;
            out[512 + (long long)b * 32 + pos] = (float)tid;
        }
    }
    if (tid < 128) {
        int n = 768 + tid;
        float v = (rk[n] < 16) ? w_s[n] : 0.f;
        out[768 + (long long)b * 128 + tid] = v;
        out[1792 + (long long)b * 128 + tid] = v;
    }
    if (tid < 32) {
        int n = 896 + tid;
        float v = (rk[n] < 3) ? w_s[n] : 0.f;
        out[2816 + (long long)b * 32 + tid] = v;
    }
}

// ---------------- launch ----------------
extern "C" void kernel_launch(void* const* d_in, const int* in_sizes, int n_in,
                              void* d_out, int out_size, void* d_ws, size_t ws_size,
                              hipStream_t stream) {
    const float* x    = (const float*)d_in[0];
    const float* imp  = (const float*)d_in[1];
    const float* W    = (const float*)d_in[2];
    const float* bias = (const float*)d_in[3];
    const float* emb  = (const float*)d_in[4];

    char* ws = (char*)d_ws;
    unsigned short* ebh = (unsigned short*)(ws + OFF_EBH);
    unsigned short* ebl = (unsigned short*)(ws + OFF_EBL);
    unsigned short* wbh = (unsigned short*)(ws + OFF_WBH);
    unsigned short* wbl = (unsigned short*)(ws + OFF_WBL);
    float* wpart        = (float*)(ws + OFF_WP);
    float* out          = (float*)d_out;

    k_prep<<<12, 256, 0, stream>>>(emb, W, ebh, ebl, wbh, wbl);
    k_mega<<<NBLK, 512, 0, stream>>>(x, bias, wbh, wbl, ebh, ebl, imp, wpart);
    k_out<<<8, 512, 0, stream>>>(wpart, out);
}

// Round 7
// 158.576 us; speedup vs baseline: 1.1571x; 1.1571x over previous
//
#include <hip/hip_runtime.h>
#include <hip/hip_bf16.h>
#include <hip/hip_fp16.h>
#include <math.h>

// ---------------- problem constants ----------------
#define ROWS  16384           // B*S
#define DM    1024
#define DS    64
#define NUSE  928             // 512+256+128+32
#define NPAD  960             // padded to 15 tiles of 64
#define RPB   32              // rows per block
#define NBLK  (ROWS/RPB)      // 512

typedef __attribute__((ext_vector_type(8))) short bf16x8;
typedef __attribute__((ext_vector_type(4))) float f32x4;

static __device__ inline f32x4 mfma16(bf16x8 a, bf16x8 b, f32x4 c) {
    return __builtin_amdgcn_mfma_f32_16x16x32_bf16(a, b, c, 0, 0, 0);
}

// split fp32 -> bf16 hi + bf16 lo (RNE both), v ~= hi + lo to ~2^-18 rel
static __device__ inline void bfsplit(float v, unsigned short& h, unsigned short& l) {
    unsigned u = __float_as_uint(v);
    unsigned hr = u + 0x7FFFu + ((u >> 16) & 1u);
    h = (unsigned short)(hr >> 16);
    float hf = __uint_as_float((unsigned)h << 16);
    float r = v - hf;
    unsigned ur = __float_as_uint(r);
    unsigned lr2 = ur + 0x7FFFu + ((ur >> 16) & 1u);
    l = (unsigned short)(lr2 >> 16);
}

// ---------------- workspace byte offsets ----------------
// eb frag-linear [kt2][q4][n960][j8] hi/lo: 122880 B each
// wb frag-linear [ktg32][q4][n64][j8] hi/lo: 131072 B each
// wpart fp32 [rc512][960]; wred fp32 [8][960]
#define OFF_EBH  0LL
#define OFF_EBL  122880LL
#define OFF_WBH  245760LL
#define OFF_WBL  376832LL
#define OFF_WP   507904LL
#define OFF_WR   2473984LL
// end 2504704 B (~2.4 MB)

// ---------------- k_prep: emb normalize+split AND W split (merged) ----------------
__global__ __launch_bounds__(256) void k_prep(const float* __restrict__ emb,
                                              const float* __restrict__ W,
                                              unsigned short* __restrict__ ebh,
                                              unsigned short* __restrict__ ebl,
                                              unsigned short* __restrict__ wbh,
                                              unsigned short* __restrict__ wbl) {
    if (blockIdx.x < 4) {
        int n = blockIdx.x * 256 + threadIdx.x;
        if (n >= NPAD) return;
        if (n >= NUSE) {
            #pragma unroll
            for (int d = 0; d < DS; d++) {
                int kt = d >> 5, q = (d >> 3) & 3, j = d & 7;
                int a = ((kt * 4 + q) * NPAD + n) * 8 + j;
                ebh[a] = 0; ebl[a] = 0;
            }
            return;
        }
        float ss = 0.f;
        #pragma unroll
        for (int d = 0; d < DS; d++) { float v = emb[n * DS + d]; ss = fmaf(v, v, ss); }
        float inv = 1.0f / sqrtf(ss);
        #pragma unroll
        for (int d = 0; d < DS; d++) {
            float v = emb[n * DS + d] * inv;
            unsigned short h, l; bfsplit(v, h, l);
            int kt = d >> 5, q = (d >> 3) & 3, j = d & 7;
            int a = ((kt * 4 + q) * NPAD + n) * 8 + j;
            ebh[a] = h; ebl[a] = l;
        }
    } else {
        int idx = (blockIdx.x - 4) * 256 + threadIdx.x;   // 0..2047
        int ktg = idx >> 6, n = idx & 63;
        #pragma unroll
        for (int q = 0; q < 4; q++) {
            #pragma unroll
            for (int j = 0; j < 8; j++) {
                int k = ktg * 32 + q * 8 + j;
                float v = W[k * DS + n];
                unsigned short h, l; bfsplit(v, h, l);
                int a = ((ktg * 4 + q) * 64 + n) * 8 + j;
                wbh[a] = h; wbl[a] = l;
            }
        }
    }
}

// ---------------- k_mega: fused x@W+b -> logits -> softmax -> weighted col-reduce ----------------
// 512 blocks x 512 thr (8 waves), 32 rows/block, LDS 79872 -> 2 blocks/CU.
// Phase A: x staged per 128-K chunk via COALESCED global reads (512 B/row segments)
//          into double-buffered LDS A-frags (bfsplit at staging); 8 waves =
//          2 rowgroups x 4 K-subgroups, conflict-free ds_read_b128 A-frags,
//          B (wb) direct from global/L2. 1 barrier per chunk.
// H-build: cooperative reduce of 4 K-partials + bias -> bf16 hi/lo A-frags.
// Phase 1: logits MFMA + exp -> Ph (fp16 LDS, aliases staging) + Z partials.
// Phase 2: weighted column reduce -> wpart.
__global__ __launch_bounds__(512, 4) void k_mega(const float* __restrict__ x,
                                                 const float* __restrict__ bias,
                                                 const unsigned short* __restrict__ wbh,
                                                 const unsigned short* __restrict__ wbl,
                                                 const unsigned short* __restrict__ ebh,
                                                 const unsigned short* __restrict__ ebl,
                                                 const float* __restrict__ imp,
                                                 float* __restrict__ wpart) {
    __shared__ __align__(16) unsigned char smem[79872];
    // region [0, 69120): phase A: Xh[2][4096]sh @0, Xl[2][4096]sh @16384; then Cb[8][1088]f @0
    //                    phase 1/2: Ph [n960][36 shorts]
    unsigned short* Ph    = (unsigned short*)smem;
    float*          Cb    = (float*)smem;
    unsigned short* Hh    = (unsigned short*)(smem + 69120);  // [kt2][q4][r32][j8]
    unsigned short* Hl    = (unsigned short*)(smem + 73216);
    float*          zslot = (float*)(smem + 77312);           // [wg4][sl4][r32]
    float*          coefL = (float*)(smem + 79360);           // [r32][sl4]

    const int tid = threadIdx.x;
    const int rc = blockIdx.x;
    const long long row0 = (long long)rc * RPB;
    const int w = tid >> 6, lane = tid & 63, q = lane >> 4, lm = lane & 15;

    zslot[tid] = 0.f;   // 512 floats exactly

    // ======== phase A: h = x@W (+bias later), staged chunks of 128 K ========
    const int rg = w >> 2, kg = w & 3;           // rowgroup, K-subgroup (32 k each)
    const int srow = tid >> 4, sjg = tid & 15;   // staging: row 0..31, j-group 0..15
    const int skt = sjg >> 2, sq = sjg & 3;
    const int sidx = ((skt * 4 + sq) * 32 + srow) * 8;
    const float* xp = &x[(row0 + srow) * (long long)DM + sjg * 8];

    f32x4 acc[4];
    #pragma unroll
    for (int f = 0; f < 4; f++) { acc[f].x = 0.f; acc[f].y = 0.f; acc[f].z = 0.f; acc[f].w = 0.f; }

    // prologue: stage chunk 0 into buf 0
    float4 pv0 = *(const float4*)&xp[0];
    float4 pv1 = *(const float4*)&xp[4];
    {
        union { uint4 u; unsigned short s[8]; } ah, al;
        bfsplit(pv0.x, ah.s[0], al.s[0]); bfsplit(pv0.y, ah.s[1], al.s[1]);
        bfsplit(pv0.z, ah.s[2], al.s[2]); bfsplit(pv0.w, ah.s[3], al.s[3]);
        bfsplit(pv1.x, ah.s[4], al.s[4]); bfsplit(pv1.y, ah.s[5], al.s[5]);
        bfsplit(pv1.z, ah.s[6], al.s[6]); bfsplit(pv1.w, ah.s[7], al.s[7]);
        *(uint4*)&((unsigned short*)(smem))[sidx]         = ah.u;
        *(uint4*)&((unsigned short*)(smem + 16384))[sidx] = al.u;
    }

    for (int ch = 0; ch < 8; ch++) {
        if (ch < 7) {   // prefetch next chunk
            pv0 = *(const float4*)&xp[(ch + 1) * 128];
            pv1 = *(const float4*)&xp[(ch + 1) * 128 + 4];
        }
        __syncthreads();   // staged buf[ch&1] visible; prior chunk's readers done
        {
            const unsigned short* XhB = (const unsigned short*)(smem + (ch & 1) * 8192);
            const unsigned short* XlB = (const unsigned short*)(smem + 16384 + (ch & 1) * 8192);
            const bf16x8 a_h = *(const bf16x8*)&XhB[((kg * 4 + q) * 32 + rg * 16 + lm) * 8];
            const bf16x8 a_l = *(const bf16x8*)&XlB[((kg * 4 + q) * 32 + rg * 16 + lm) * 8];
            const int ktg = ch * 4 + kg;
            #pragma unroll
            for (int f = 0; f < 4; f++) {
                const int ba = ((ktg * 4 + q) * 64 + f * 16 + lm) * 8;
                const bf16x8 b_h = *(const bf16x8*)&wbh[ba];
                const bf16x8 b_l = *(const bf16x8*)&wbl[ba];
                acc[f] = mfma16(a_h, b_h, acc[f]);
                acc[f] = mfma16(a_h, b_l, acc[f]);
                acc[f] = mfma16(a_l, b_h, acc[f]);
            }
        }
        if (ch < 7) {   // stage next chunk into the other buffer
            union { uint4 u; unsigned short s[8]; } ah, al;
            bfsplit(pv0.x, ah.s[0], al.s[0]); bfsplit(pv0.y, ah.s[1], al.s[1]);
            bfsplit(pv0.z, ah.s[2], al.s[2]); bfsplit(pv0.w, ah.s[3], al.s[3]);
            bfsplit(pv1.x, ah.s[4], al.s[4]); bfsplit(pv1.y, ah.s[5], al.s[5]);
            bfsplit(pv1.z, ah.s[6], al.s[6]); bfsplit(pv1.w, ah.s[7], al.s[7]);
            *(uint4*)&((unsigned short*)(smem + ((ch + 1) & 1) * 8192))[sidx]         = ah.u;
            *(uint4*)&((unsigned short*)(smem + 16384 + ((ch + 1) & 1) * 8192))[sidx] = al.u;
        }
    }
    __syncthreads();   // all MFMA reads of X buffers done -> Cb may overwrite

    // write per-wave K-partials to Cb
    #pragma unroll
    for (int f = 0; f < 4; f++)
        #pragma unroll
        for (int t = 0; t < 4; t++)
            Cb[w * 1088 + (q * 4 + t) * 68 + f * 16 + lm] = acc[f][t];
    __syncthreads();

    // ======== H-build: reduce 4 kg partials + bias -> split A-frags ========
    {
        const int r = tid >> 4, seg = tid & 15;
        const int rgg = r >> 4, rl = r & 15;
        const int c0 = seg * 4;
        float4 s = *(const float4*)&bias[c0];
        #pragma unroll
        for (int g = 0; g < 4; g++) {
            float4 a = *(const float4*)&Cb[(rgg * 4 + g) * 1088 + rl * 68 + c0];
            s.x += a.x; s.y += a.y; s.z += a.z; s.w += a.w;
        }
        __syncthreads();   // Cb reads done before Ph (alias) writes in phase 1
        unsigned short h0, l0, h1, l1, h2, l2, h3, l3;
        bfsplit(s.x, h0, l0); bfsplit(s.y, h1, l1);
        bfsplit(s.z, h2, l2); bfsplit(s.w, h3, l3);
        const int ktH = c0 >> 5, qH = (c0 >> 3) & 3, jH = c0 & 7;   // jH = 0 or 4
        const int base = ((ktH * 4 + qH) * 32 + r) * 8 + jH;
        uint2 ph; ph.x = (unsigned)h0 | ((unsigned)h1 << 16); ph.y = (unsigned)h2 | ((unsigned)h3 << 16);
        uint2 pl; pl.x = (unsigned)l0 | ((unsigned)l1 << 16); pl.y = (unsigned)l2 | ((unsigned)l3 << 16);
        *(uint2*)&Hh[base] = ph;
        *(uint2*)&Hl[base] = pl;
    }
    __syncthreads();

    // ======== phase 1: logits + exp -> Ph, Z partials ========
    const int wg = w & 3, rgp = w >> 2;
    bf16x8 a_h[2], a_l[2];
    #pragma unroll
    for (int kt = 0; kt < 2; kt++) {
        const int ab = ((kt * 4 + q) * 32 + rgp * 16 + lm) * 8;
        a_h[kt] = *(const bf16x8*)&Hh[ab];
        a_l[kt] = *(const bf16x8*)&Hl[ab];
    }

    #pragma unroll
    for (int v = 0; v < 4; v++) {
        const int nt = wg + v * 4;
        if (nt > 14) continue;
        f32x4 acc2[4];
        #pragma unroll
        for (int f = 0; f < 4; f++) { acc2[f].x = 0.f; acc2[f].y = 0.f; acc2[f].z = 0.f; acc2[f].w = 0.f; }
        #pragma unroll
        for (int kt = 0; kt < 2; kt++) {
            #pragma unroll
            for (int f = 0; f < 4; f++) {
                const int bb = ((kt * 4 + q) * NPAD + nt * 64 + f * 16 + lm) * 8;
                const bf16x8 b_h = *(const bf16x8*)&ebh[bb];
                const bf16x8 b_l = *(const bf16x8*)&ebl[bb];
                acc2[f] = mfma16(a_h[kt], b_h, acc2[f]);
                acc2[f] = mfma16(a_h[kt], b_l, acc2[f]);
                acc2[f] = mfma16(a_l[kt], b_h, acc2[f]);
            }
        }
        const int sl = (nt < 8) ? 0 : (nt < 12) ? 1 : (nt < 14) ? 2 : 3;
        float s0 = 0.f, s1 = 0.f, s2 = 0.f, s3 = 0.f;
        #pragma unroll
        for (int f = 0; f < 4; f++) {
            float e0 = __expf(acc2[f][0]);
            float e1 = __expf(acc2[f][1]);
            float e2 = __expf(acc2[f][2]);
            float e3 = __expf(acc2[f][3]);
            const int n = nt * 64 + f * 16 + lm;
            unsigned short p0 = __half_as_ushort(__float2half(e0));
            unsigned short p1 = __half_as_ushort(__float2half(e1));
            unsigned short p2 = __half_as_ushort(__float2half(e2));
            unsigned short p3 = __half_as_ushort(__float2half(e3));
            uint2 pk; pk.x = (unsigned)p0 | ((unsigned)p1 << 16); pk.y = (unsigned)p2 | ((unsigned)p3 << 16);
            *(uint2*)&Ph[n * 36 + rgp * 16 + q * 4] = pk;
            if (nt * 64 + f * 16 < NUSE) {   // exclude pad cols (nt14 f2,f3)
                s0 += e0; s1 += e1; s2 += e2; s3 += e3;
            }
        }
        #pragma unroll
        for (int off = 1; off < 16; off <<= 1) {
            s0 += __shfl_xor(s0, off); s1 += __shfl_xor(s1, off);
            s2 += __shfl_xor(s2, off); s3 += __shfl_xor(s3, off);
        }
        if (lm < 4) {
            float sv = (lm == 0) ? s0 : (lm == 1) ? s1 : (lm == 2) ? s2 : s3;
            zslot[(wg * 4 + sl) * 32 + rgp * 16 + q * 4 + lm] += sv;   // per-wg slots: no race
        }
    }
    __syncthreads();

    // ---- Z + coef ----
    if (tid < 32) {
        const int r = tid;
        const float im = imp[row0 + r];
        #pragma unroll
        for (int sl = 0; sl < 4; sl++) {
            float Z = zslot[(0 * 4 + sl) * 32 + r] + zslot[(1 * 4 + sl) * 32 + r]
                    + zslot[(2 * 4 + sl) * 32 + r] + zslot[(3 * 4 + sl) * 32 + r];
            coefL[r * 4 + sl] = im / Z;
        }
    }
    __syncthreads();

    // ======== phase 2: weighted column reduce ========
    for (int nn = tid; nn < NUSE; nn += 512) {
        const int sl = (nn < 512) ? 0 : (nn < 768) ? 1 : (nn < 896) ? 2 : 3;
        float accw = 0.f;
        #pragma unroll
        for (int rb = 0; rb < 8; rb++) {
            uint2 pk = *(const uint2*)&Ph[nn * 36 + rb * 4];
            float v0 = __half2float(__ushort_as_half((unsigned short)(pk.x & 0xFFFF)));
            float v1 = __half2float(__ushort_as_half((unsigned short)(pk.x >> 16)));
            float v2 = __half2float(__ushort_as_half((unsigned short)(pk.y & 0xFFFF)));
            float v3 = __half2float(__ushort_as_half((unsigned short)(pk.y >> 16)));
            const int row = rb * 4;
            accw = fmaf(coefL[(row + 0) * 4 + sl], v0, accw);
            accw = fmaf(coefL[(row + 1) * 4 + sl], v1, accw);
            accw = fmaf(coefL[(row + 2) * 4 + sl], v2, accw);
            accw = fmaf(coefL[(row + 3) * 4 + sl], v3, accw);
        }
        wpart[(long long)rc * NPAD + nn] = accw;
    }
}

// ---------------- k_red: parallel chunk-reduction wpart[512][960] -> wred[8][960] ----------------
// grid (29 n-groups of 32, 8 batches) x 256 thr: coalesced, fixed order (deterministic)
__global__ __launch_bounds__(256) void k_red(const float* __restrict__ wpart,
                                             float* __restrict__ wred) {
    const int g = blockIdx.x;       // 0..28  (29*32 = 928 = NUSE)
    const int b = blockIdx.y;       // 0..7
    const int tid = threadIdx.x;
    const int n = g * 32 + (tid & 31);
    const int cp = tid >> 5;        // 0..7
    float s = 0.f;
    #pragma unroll 2
    for (int c = cp; c < 64; c += 8)
        s += wpart[(long long)(b * 64 + c) * NPAD + n];
    __shared__ float red[8][32];
    red[cp][tid & 31] = s;
    __syncthreads();
    if (tid < 32) {
        float t = 0.f;
        #pragma unroll
        for (int p = 0; p < 8; p++) t += red[p][tid];
        wred[b * 960 + g * 32 + tid] = t;
    }
}

// ---------------- k_rank: ranks + outputs from wred ----------------
// out layout (floats): idx_qk[8][64] @0, idx_v[8][32] @512, rw_Q[8][128] @768,
// rw_K[8][128] @1792, vw[8][32] @2816, w_qk[8][512] @3072, w_v[8][256] @7168
__global__ __launch_bounds__(512) void k_rank(const float* __restrict__ wred,
                                              float* __restrict__ out) {
    const int b = blockIdx.x;
    const int tid = threadIdx.x;
    __shared__ float w_s[NUSE];
    __shared__ int   rk[NUSE];

    for (int n = tid; n < NUSE; n += 512) {
        float s = wred[b * 960 + n];
        w_s[n] = s;
        if (n < 512)      out[3072 + (long long)b * 512 + n] = s;
        else if (n < 768) out[7168 + (long long)b * 256 + (n - 512)] = s;
    }
    __syncthreads();

    for (int n = tid; n < NUSE; n += 512) {
        int lo, hi;
        if (n < 512)      { lo = 0;   hi = 512; }
        else if (n < 768) { lo = 512; hi = 768; }
        else if (n < 896) { lo = 768; hi = 896; }
        else              { lo = 896; hi = NUSE; }
        float wn = w_s[n];
        int r = 0;
        for (int m = lo; m < hi; m++) {
            float wm = w_s[m];
            r += (wm > wn) || ((wm == wn) && (m < n));
        }
        rk[n] = r;
    }
    __syncthreads();

    if (tid < 512) {
        int n = tid;
        if (rk[n] < 64) {
            int pos = 0;
            for (int m = 0; m < n; m++) pos += (rk[m] < 64) ? 1 : 0;
            out[(long long)b * 64 + pos] = (float)n;
        }
    }
    if (tid < 256) {
        int n = 512 + tid;
        if (rk[n] < 32) {
            int pos = 0;
            for (int m = 512; m < n; m++) pos += (rk[m] < 32) ? 1 : 0;
            out[512 + (long long)b * 32 + pos] = (float)tid;
        }
    }
    if (tid < 128) {
        int n = 768 + tid;
        float v = (rk[n] < 16) ? w_s[n] : 0.f;
        out[768 + (long long)b * 128 + tid] = v;
        out[1792 + (long long)b * 128 + tid] = v;
    }
    if (tid < 32) {
        int n = 896 + tid;
        float v = (rk[n] < 3) ? w_s[n] : 0.f;
        out[2816 + (long long)b * 32 + tid] = v;
    }
}

// ---------------- launch ----------------
extern "C" void kernel_launch(void* const* d_in, const int* in_sizes, int n_in,
                              void* d_out, int out_size, void* d_ws, size_t ws_size,
                              hipStream_t stream) {
    const float* x    = (const float*)d_in[0];
    const float* imp  = (const float*)d_in[1];
    const float* W    = (const float*)d_in[2];
    const float* bias = (const float*)d_in[3];
    const float* emb  = (const float*)d_in[4];

    char* ws = (char*)d_ws;
    unsigned short* ebh = (unsigned short*)(ws + OFF_EBH);
    unsigned short* ebl = (unsigned short*)(ws + OFF_EBL);
    unsigned short* wbh = (unsigned short*)(ws + OFF_WBH);
    unsigned short* wbl = (unsigned short*)(ws + OFF_WBL);
    float* wpart        = (float*)(ws + OFF_WP);
    float* wred         = (float*)(ws + OFF_WR);
    float* out          = (float*)d_out;

    k_prep<<<12, 256, 0, stream>>>(emb, W, ebh, ebl, wbh, wbl);
    k_mega<<<NBLK, 512, 0, stream>>>(x, bias, wbh, wbl, ebh, ebl, imp, wpart);
    k_red<<<dim3(29, 8), 256, 0, stream>>>(wpart, wred);
    k_rank<<<8, 512, 0, stream>>>(wred, out);
}